// Round 7
// baseline (259.139 us; speedup 1.0000x reference)
//
#include <hip/hip_runtime.h>
#include <hip/hip_bf16.h>

typedef __hip_bfloat16 bf16;
typedef float v4f __attribute__((ext_vector_type(4)));
typedef short v8s __attribute__((ext_vector_type(8)));

typedef const __attribute__((address_space(1))) void gvoid;
typedef __attribute__((address_space(3))) void lvoid;

__device__ __forceinline__ void async16(const void* g, void* l) {
  __builtin_amdgcn_global_load_lds((gvoid*)g, (lvoid*)l, 16, 0, 0);
}

// cardinal cubic B-spline on [0,4], 0 outside. Reference bspline(t) == b3(4t),
// wavelet(t) == b3(8t) - b3(8t-4). Clamp makes u>=4 exactly 0 (64-108+48-4).
__device__ __forceinline__ float b3(float u) {
  u = fminf(fmaxf(u, 0.f), 4.f);
  float t1 = fmaxf(u - 1.f, 0.f);
  float t2 = fmaxf(u - 2.f, 0.f);
  float t3 = fmaxf(u - 3.f, 0.f);
  float c0 = u * u * u;
  float c1 = t1 * t1 * t1;
  float c2 = t2 * t2 * t2;
  float c3 = t3 * t3 * t3;
  return (c0 - 4.f * c1 + 6.f * c2 - 4.f * c3) * (1.f / 6.f);
}

// m97-style NT GEMM mainloop: C[128 x NI*32] tile, BK elems per stage,
// bf16 MFMA 16x16x32. A: [*, lda] row-major (M rows), B: [*, ldb] row-major
// (N rows, i.e. B^T). As: 128*BK bf16, Bs: NI*32*BK bf16.
template <int NI, int BK>
__device__ __forceinline__ void mfma_loop(const bf16* __restrict__ A,
                                          const bf16* __restrict__ B, int lda,
                                          int ldb, int kLen, bf16* As, bf16* Bs,
                                          v4f acc[4][NI]) {
  const int tid = threadIdx.x;
  const int wave = tid >> 6;
  const int lane = tid & 63;
  const int quad = lane >> 4;
  const int r16 = lane & 15;
  const int wm = (wave >> 1) * 64;
  const int wn = (wave & 1) * (NI * 16);
  constexpr int CPR = BK / 8;          // 16B chunks per row
  constexpr int AQ = 128 * CPR / 256;  // async groups for A
  constexpr int BQ = NI * 32 * CPR / 256;
  char* AsC = (char*)As;
  char* BsC = (char*)Bs;
  for (int kk = 0; kk < kLen; kk += BK) {
#pragma unroll
    for (int q = 0; q < AQ; ++q) {
      const int ch = tid + 256 * q;
      const int r = ch / CPR, c = (ch % CPR) * 8;
      async16(A + (size_t)r * lda + kk + c, AsC + q * 4096 + wave * 1024);
    }
#pragma unroll
    for (int q = 0; q < BQ; ++q) {
      const int ch = tid + 256 * q;
      const int r = ch / CPR, c = (ch % CPR) * 8;
      async16(B + (size_t)r * ldb + kk + c, BsC + q * 4096 + wave * 1024);
    }
    __syncthreads();
#pragma unroll
    for (int ks = 0; ks < BK / 32; ++ks) {
      v8s af[4], bfr[NI];
#pragma unroll
      for (int mi = 0; mi < 4; ++mi)
        af[mi] =
            *(const v8s*)(As + (wm + mi * 16 + r16) * BK + ks * 32 + quad * 8);
#pragma unroll
      for (int ni = 0; ni < NI; ++ni)
        bfr[ni] =
            *(const v8s*)(Bs + (wn + ni * 16 + r16) * BK + ks * 32 + quad * 8);
#pragma unroll
      for (int mi = 0; mi < 4; ++mi)
#pragma unroll
        for (int ni = 0; ni < NI; ++ni)
          acc[mi][ni] = __builtin_amdgcn_mfma_f32_16x16x32_bf16(
              af[mi], bfr[ni], acc[mi][ni], 0, 0, 0);
    }
    __syncthreads();
  }
}

// per-row: sq-norm + bf16 cast of x into U[:, 0:256]
__global__ void prep(const float* __restrict__ x, bf16* __restrict__ U,
                     float* __restrict__ sq) {
  const int n = blockIdx.x, b = blockIdx.y, t = threadIdx.x;
  const size_t row = (size_t)b * 4096 + n;
  float v = x[row * 256 + t];
  U[row * 1280 + t] = __float2bfloat16(v);
  float s = v * v;
#pragma unroll
  for (int o = 32; o > 0; o >>= 1) s += __shfl_down(s, o, 64);
  __shared__ float ls[4];
  if ((t & 63) == 0) ls[t >> 6] = s;
  __syncthreads();
  if (t == 0) sq[row] = ls[0] + ls[1] + ls[2] + ls[3];
}

// fp32 [z][4096][256] -> bf16 [z][256][4096] (tiled transpose via LDS)
__global__ void transk(const float* __restrict__ src, bf16* __restrict__ dst) {
  __shared__ float tile[64][65];
  const int z = blockIdx.z;
  const float* s = src + (size_t)z * 4096 * 256;
  bf16* d = dst + (size_t)z * 256 * 4096;
  const int n0 = blockIdx.x * 64, d0 = blockIdx.y * 64;
  const int tx = threadIdx.x & 31, ty = threadIdx.x >> 5;
#pragma unroll
  for (int i = 0; i < 8; ++i) {
    const int r = ty + i * 8;
    const float2 v = *(const float2*)(s + (size_t)(n0 + r) * 256 + d0 + tx * 2);
    tile[r][tx * 2] = v.x;
    tile[r][tx * 2 + 1] = v.y;
  }
  __syncthreads();
#pragma unroll
  for (int i = 0; i < 8; ++i) {
    const int c = ty + i * 8;
    __hip_bfloat162 p;
    p.x = __float2bfloat16(tile[tx * 2][c]);
    p.y = __float2bfloat16(tile[tx * 2 + 1][c]);
    *(__hip_bfloat162*)(d + (size_t)(d0 + c) * 4096 + n0 + tx * 2) = p;
  }
}

// WbigT bf16 [128][1280]
__global__ void wbig(const float* __restrict__ Wk, const float* __restrict__ Wl,
                     bf16* __restrict__ WbT) {
  int idx = blockIdx.x * 256 + threadIdx.x;
  if (idx >= 128 * 1280) return;
  int j = idx / 1280, k = idx % 1280;
  int o = j & 63;
  float v = 0.f;
  if (k < 256)
    v = Wk[k * 64 + o] + Wl[k * 128 + j];
  else if (k < 512)
    v = (j < 64) ? Wk[16384 + (k - 256) * 64 + o] : 0.f;
  else if (k < 768)
    v = (j < 64) ? Wk[32768 + (k - 512) * 64 + o] : 0.f;
  else if (k < 1024)
    v = (j >= 64) ? Wk[16384 + (k - 768) * 64 + o] : 0.f;
  else
    v = (j >= 64) ? Wk[32768 + (k - 1024) * 64 + o] : 0.f;
  WbT[idx] = __float2bfloat16(v);
}

// S = x x^T tile + adjacency/spline epilogue -> bk, wk bf16 [4096][4096].
// Spline pair via 2048-entry LDS LUT over t=exp(-d2/512) in (0,1].
// Bin error ~1.5e-3 ~ bf16 quantum << 2% threshold.
// Paired-column dword stores via shfl_xor(1).
// LDS = 16K As + 16K Bs + 8K lut = 40K; bounds(256,3): 3 blocks/CU with
// VGPR budget 170 (R6's bounds=4 capped at 128 -> scratch spills, WRITE
// +16MB, dur 58->70us regression).
__global__ __launch_bounds__(256, 3) void gemm_s(const bf16* __restrict__ U,
                                                 const float* __restrict__ sq,
                                                 bf16* __restrict__ kmat) {
  __shared__ __align__(16) bf16 As[128 * 64];
  __shared__ __align__(16) bf16 Bs[128 * 64];
  __shared__ unsigned lut[2048];
  const int tid = threadIdx.x;
  for (int i = tid; i < 2048; i += 256) {
    float t = (i + 0.5f) * (1.f / 2048.f);
    float bv = b3(4.f * t);
    float wv = b3(8.f * t) - b3(8.f * t - 4.f);
    __hip_bfloat162 p;
    p.x = __float2bfloat16(bv);  // low 16 = b-kernel
    p.y = __float2bfloat16(wv);  // high 16 = wavelet
    lut[i] = *(unsigned*)&p;
  }
  const int z = blockIdx.z;
  const bf16* A = U + (size_t)z * 4096 * 1280 + (size_t)blockIdx.x * 128 * 1280;
  const bf16* B = U + (size_t)z * 4096 * 1280 + (size_t)blockIdx.y * 128 * 1280;
  v4f acc[4][4];
#pragma unroll
  for (int a = 0; a < 4; ++a)
#pragma unroll
    for (int b2 = 0; b2 < 4; ++b2) acc[a][b2] = (v4f){0.f, 0.f, 0.f, 0.f};
  mfma_loop<4, 64>(A, B, 1280, 1280, 256, As, Bs, acc);
  const int wave = tid >> 6, lane = tid & 63;
  const int quad = lane >> 4, r16 = lane & 15;
  const int wm = (wave >> 1) * 64, wn = (wave & 1) * 64;
  const float* sqr = sq + (size_t)z * 4096;
  unsigned short* bk = (unsigned short*)(kmat + (size_t)(z * 2) * 4096 * 4096);
  unsigned short* wk = bk + (size_t)4096 * 4096;
  const int i0 = blockIdx.x * 128 + wm + quad * 4;
  const int j0 = blockIdx.y * 128 + wn + r16;
  const int par = lane & 1;  // 0: stores rows r=0,1 ; 1: rows r=2,3
  const int jc = j0 - par;   // even column of this lane's pair
  float sqj[4];
#pragma unroll
  for (int ni = 0; ni < 4; ++ni) sqj[ni] = sqr[j0 + ni * 16];
  const float c = -1.4426950408889634f / 512.f;  // -log2(e)/512
#pragma unroll
  for (int mi = 0; mi < 4; ++mi) {
#pragma unroll
    for (int ni = 0; ni < 4; ++ni) {
      unsigned pv[4];
#pragma unroll
      for (int r = 0; r < 4; ++r) {
        float s = acc[mi][ni][r];
        float d2 = fmaxf(sqr[i0 + mi * 16 + r] + sqj[ni] - 2.f * s, 0.f);
        float t = __builtin_amdgcn_exp2f(d2 * c);
        int idx = (int)fminf(t * 2048.f, 2047.f);
        pv[r] = lut[idx];
      }
      unsigned ov[4];
#pragma unroll
      for (int r = 0; r < 4; ++r) ov[r] = __shfl_xor((int)pv[r], 1, 64);
#pragma unroll
      for (int rr = 0; rr < 2; ++rr) {
        const int r = par * 2 + rr;
        const unsigned a = pv[r], b2 = ov[r];
        const unsigned lo = par ? b2 : a;  // left (even) column
        const unsigned hi = par ? a : b2;  // right (odd) column
        const unsigned bkd = (lo & 0xffffu) | (hi << 16);
        const unsigned wkd = (lo >> 16) | (hi & 0xffff0000u);
        const int i = i0 + mi * 16 + r;
        const size_t off = (size_t)i * 4096 + jc + ni * 16;
        *(unsigned*)(bk + off) = bkd;
        *(unsigned*)(wk + off) = wkd;
      }
    }
  }
}

// h-partial = K[:, split] @ H[split, :] : split-K x4, BK=64, 128x128 tile.
// A = kernel matrix [4096][4096] bf16, Bt = H^T bf16 [256][4096].
// writes fp32 partial to hpart[split][z][4096][256].
__global__ __launch_bounds__(256, 4) void gemm_h(const bf16* __restrict__ kmat,
                                                 const bf16* __restrict__ BtBase,
                                                 float* __restrict__ hpart,
                                                 int btShift) {
  __shared__ __align__(16) bf16 As[128 * 64];
  __shared__ __align__(16) bf16 Bs[128 * 64];
  const int bz = blockIdx.z;
  const int z = bz >> 2, split = bz & 3;
  const int kk0 = split * 1024;
  const bf16* A =
      kmat + (size_t)z * 4096 * 4096 + (size_t)blockIdx.x * 128 * 4096 + kk0;
  const bf16* B = BtBase + (size_t)(z >> btShift) * 256 * 4096 +
                  (size_t)blockIdx.y * 128 * 4096 + kk0;
  v4f acc[4][4];
#pragma unroll
  for (int a = 0; a < 4; ++a)
#pragma unroll
    for (int b2 = 0; b2 < 4; ++b2) acc[a][b2] = (v4f){0.f, 0.f, 0.f, 0.f};
  mfma_loop<4, 64>(A, B, 4096, 4096, 1024, As, Bs, acc);
  const int tid = threadIdx.x, wave = tid >> 6, lane = tid & 63;
  const int quad = lane >> 4, r16 = lane & 15;
  const int wm = (wave >> 1) * 64, wn = (wave & 1) * 64;
  float* H = hpart + ((size_t)split * 4 + z) * 4096 * 256;
  const int i0 = blockIdx.x * 128 + wm + quad * 4;
  const int j0 = blockIdx.y * 128 + wn + r16;
#pragma unroll
  for (int mi = 0; mi < 4; ++mi)
#pragma unroll
    for (int r = 0; r < 4; ++r) {
      const int i = i0 + mi * 16 + r;
#pragma unroll
      for (int ni = 0; ni < 4; ++ni)
        H[(size_t)i * 256 + j0 + ni * 16] = acc[mi][ni][r];
    }
}

// sum the four split-K partials; write bf16 slice into U[:, uoff..] and
// (pass 1 only) transposed bf16 into hT [z][256][4096].
__global__ void reduceT(const float* __restrict__ hpart, bf16* __restrict__ U,
                        bf16* __restrict__ hT, int uoffBase) {
  __shared__ float tile[64][65];
  const int z = blockIdx.z;
  const int b = z >> 1, kern = z & 1;
  const int uoff = uoffBase + kern * 512;
  const int n0 = blockIdx.x * 64, d0 = blockIdx.y * 64;
  const int tx = threadIdx.x & 31, ty = threadIdx.x >> 5;
  const size_t sstride = (size_t)4 * 4096 * 256;
  const float* s0 = hpart + (size_t)z * 4096 * 256;
#pragma unroll
  for (int i = 0; i < 8; ++i) {
    const int r = ty + i * 8;
    const size_t off = (size_t)(n0 + r) * 256 + d0 + tx * 2;
    float vx = 0.f, vy = 0.f;
#pragma unroll
    for (int k = 0; k < 4; ++k) {
      const float2 a = *(const float2*)(s0 + k * sstride + off);
      vx += a.x;
      vy += a.y;
    }
    tile[r][tx * 2] = vx;
    tile[r][tx * 2 + 1] = vy;
    __hip_bfloat162 p;
    p.x = __float2bfloat16(vx);
    p.y = __float2bfloat16(vy);
    *(__hip_bfloat162*)(U + (size_t)(b * 4096 + n0 + r) * 1280 + uoff + d0 +
                        tx * 2) = p;
  }
  if (hT) {
    __syncthreads();
#pragma unroll
    for (int i = 0; i < 8; ++i) {
      const int c = ty + i * 8;
      __hip_bfloat162 p;
      p.x = __float2bfloat16(tile[tx * 2][c]);
      p.y = __float2bfloat16(tile[tx * 2 + 1][c]);
      *(__hip_bfloat162*)(hT + (size_t)z * 256 * 4096 + (size_t)(d0 + c) * 4096 +
                          n0 + tx * 2) = p;
    }
  }
}

// out = relu(U @ Wbig + b_lin), M=8192, K=1280, N=128
__global__ __launch_bounds__(256, 4) void gemm_proj(
    const bf16* __restrict__ U, const bf16* __restrict__ WbT,
    const float* __restrict__ blin, float* __restrict__ out) {
  __shared__ __align__(16) bf16 As[128 * 64];
  __shared__ __align__(16) bf16 Bs[64 * 64];
  const bf16* A = U + (size_t)blockIdx.x * 128 * 1280;
  const bf16* B = WbT + (size_t)blockIdx.y * 64 * 1280;
  v4f acc[4][2];
#pragma unroll
  for (int a = 0; a < 4; ++a)
#pragma unroll
    for (int b2 = 0; b2 < 2; ++b2) acc[a][b2] = (v4f){0.f, 0.f, 0.f, 0.f};
  mfma_loop<2, 64>(A, B, 1280, 1280, 1280, As, Bs, acc);
  const int tid = threadIdx.x, wave = tid >> 6, lane = tid & 63;
  const int quad = lane >> 4, r16 = lane & 15;
  const int wm = (wave >> 1) * 64, wn = (wave & 1) * 32;
  const int i0 = blockIdx.x * 128 + wm + quad * 4;
  const int j0 = blockIdx.y * 64 + wn + r16;
#pragma unroll
  for (int mi = 0; mi < 4; ++mi)
#pragma unroll
    for (int r = 0; r < 4; ++r) {
      const int i = i0 + mi * 16 + r;
#pragma unroll
      for (int ni = 0; ni < 2; ++ni) {
        const int j = j0 + ni * 16;
        out[(size_t)i * 128 + j] = fmaxf(acc[mi][ni][r] + blin[j], 0.f);
      }
    }
}

extern "C" void kernel_launch(void* const* d_in, const int* in_sizes, int n_in,
                              void* d_out, int out_size, void* d_ws,
                              size_t ws_size, hipStream_t stream) {
  const float* x = (const float*)d_in[0];
  const float* Wk = (const float*)d_in[1];
  const float* Wlin = (const float*)d_in[2];
  const float* blin = (const float*)d_in[3];
  float* out = (float*)d_out;
  char* w = (char*)d_ws;
  // workspace layout (bytes):
  bf16* kmat = (bf16*)(w);                 // 4 * 4096*4096 * 2  = 134217728
  float* hpart = (float*)(w + 134217728);  // 4 * 4*4096*256*4   = 67108864
  bf16* h1T = (bf16*)(w + 201326592);      // 4 * 256*4096 * 2   = 8388608
  bf16* xhT = (bf16*)(w + 209715200);      // 2 * 256*4096 * 2   = 4194304
  bf16* U = (bf16*)(w + 213909504);        // 8192*1280 * 2      = 20971520
  bf16* WbT = (bf16*)(w + 234881024);      // 128*1280 * 2       = 327680
  float* sqv = (float*)(w + 235208704);    // 8192 * 4           = 32768
  // total ~235.2 MB

  prep<<<dim3(4096, 2), 256, 0, stream>>>(x, U, sqv);
  transk<<<dim3(64, 4, 2), 256, 0, stream>>>(x, xhT);
  wbig<<<dim3(640), 256, 0, stream>>>(Wk, Wlin, WbT);
  gemm_s<<<dim3(32, 32, 2), 256, 0, stream>>>(U, sqv, kmat);
  // pass 1: h1 = K @ x
  gemm_h<<<dim3(32, 2, 16), 256, 0, stream>>>(kmat, xhT, hpart, 1);
  reduceT<<<dim3(64, 4, 4), 256, 0, stream>>>(hpart, U, h1T, 256);
  // pass 2: h2 = K @ h1
  gemm_h<<<dim3(32, 2, 16), 256, 0, stream>>>(kmat, h1T, hpart, 0);
  reduceT<<<dim3(64, 4, 4), 256, 0, stream>>>(hpart, U, nullptr, 512);
  gemm_proj<<<dim3(64, 2), 256, 0, stream>>>(U, WbT, blin, out);
}

// Round 8
// 243.660 us; speedup vs baseline: 1.0635x; 1.0635x over previous
//
#include <hip/hip_runtime.h>
#include <hip/hip_bf16.h>

typedef __hip_bfloat16 bf16;
typedef float v4f __attribute__((ext_vector_type(4)));
typedef short v8s __attribute__((ext_vector_type(8)));

typedef const __attribute__((address_space(1))) void gvoid;
typedef __attribute__((address_space(3))) void lvoid;

__device__ __forceinline__ void async16(const void* g, void* l) {
  __builtin_amdgcn_global_load_lds((gvoid*)g, (lvoid*)l, 16, 0, 0);
}

__device__ __forceinline__ unsigned short f2bf(float v) {
  __hip_bfloat16 h = __float2bfloat16(v);
  return *(unsigned short*)&h;
}
__device__ __forceinline__ float bflo(unsigned dw) {
  unsigned u = dw << 16;
  return *(float*)&u;
}
__device__ __forceinline__ float bfhi(unsigned dw) {
  unsigned u = dw & 0xffff0000u;
  return *(float*)&u;
}

// cardinal cubic B-spline on [0,4], 0 outside. Reference bspline(t) == b3(4t),
// wavelet(t) == b3(8t) - b3(8t-4). Clamp makes u>=4 exactly 0 (64-108+48-4).
__device__ __forceinline__ float b3(float u) {
  u = fminf(fmaxf(u, 0.f), 4.f);
  float t1 = fmaxf(u - 1.f, 0.f);
  float t2 = fmaxf(u - 2.f, 0.f);
  float t3 = fmaxf(u - 3.f, 0.f);
  float c0 = u * u * u;
  float c1 = t1 * t1 * t1;
  float c2 = t2 * t2 * t2;
  float c3 = t3 * t3 * t3;
  return (c0 - 4.f * c1 + 6.f * c2 - 4.f * c3) * (1.f / 6.f);
}

// m97-style NT GEMM mainloop: C[128 x NI*32] tile, BK elems per stage,
// bf16 MFMA 16x16x32. A: [*, lda] row-major (M rows), B: [*, ldb] row-major
// (N rows, i.e. B^T). As: 128*BK bf16, Bs: NI*32*BK bf16.
template <int NI, int BK>
__device__ __forceinline__ void mfma_loop(const bf16* __restrict__ A,
                                          const bf16* __restrict__ B, int lda,
                                          int ldb, int kLen, bf16* As, bf16* Bs,
                                          v4f acc[4][NI]) {
  const int tid = threadIdx.x;
  const int wave = tid >> 6;
  const int lane = tid & 63;
  const int quad = lane >> 4;
  const int r16 = lane & 15;
  const int wm = (wave >> 1) * 64;
  const int wn = (wave & 1) * (NI * 16);
  constexpr int CPR = BK / 8;          // 16B chunks per row
  constexpr int AQ = 128 * CPR / 256;  // async groups for A
  constexpr int BQ = NI * 32 * CPR / 256;
  char* AsC = (char*)As;
  char* BsC = (char*)Bs;
  for (int kk = 0; kk < kLen; kk += BK) {
#pragma unroll
    for (int q = 0; q < AQ; ++q) {
      const int ch = tid + 256 * q;
      const int r = ch / CPR, c = (ch % CPR) * 8;
      async16(A + (size_t)r * lda + kk + c, AsC + q * 4096 + wave * 1024);
    }
#pragma unroll
    for (int q = 0; q < BQ; ++q) {
      const int ch = tid + 256 * q;
      const int r = ch / CPR, c = (ch % CPR) * 8;
      async16(B + (size_t)r * ldb + kk + c, BsC + q * 4096 + wave * 1024);
    }
    __syncthreads();
#pragma unroll
    for (int ks = 0; ks < BK / 32; ++ks) {
      v8s af[4], bfr[NI];
#pragma unroll
      for (int mi = 0; mi < 4; ++mi)
        af[mi] =
            *(const v8s*)(As + (wm + mi * 16 + r16) * BK + ks * 32 + quad * 8);
#pragma unroll
      for (int ni = 0; ni < NI; ++ni)
        bfr[ni] =
            *(const v8s*)(Bs + (wn + ni * 16 + r16) * BK + ks * 32 + quad * 8);
#pragma unroll
      for (int mi = 0; mi < 4; ++mi)
#pragma unroll
        for (int ni = 0; ni < NI; ++ni)
          acc[mi][ni] = __builtin_amdgcn_mfma_f32_16x16x32_bf16(
              af[mi], bfr[ni], acc[mi][ni], 0, 0, 0);
    }
    __syncthreads();
  }
}

// per-row: sq-norm + bf16 cast of x into U[:, 0:256]
__global__ void prep(const float* __restrict__ x, bf16* __restrict__ U,
                     float* __restrict__ sq) {
  const int n = blockIdx.x, b = blockIdx.y, t = threadIdx.x;
  const size_t row = (size_t)b * 4096 + n;
  float v = x[row * 256 + t];
  U[row * 1280 + t] = __float2bfloat16(v);
  float s = v * v;
#pragma unroll
  for (int o = 32; o > 0; o >>= 1) s += __shfl_down(s, o, 64);
  __shared__ float ls[4];
  if ((t & 63) == 0) ls[t >> 6] = s;
  __syncthreads();
  if (t == 0) sq[row] = ls[0] + ls[1] + ls[2] + ls[3];
}

// fp32 [z][4096][256] -> bf16 [z][256][4096] (tiled transpose via LDS)
__global__ void transk(const float* __restrict__ src, bf16* __restrict__ dst) {
  __shared__ float tile[64][65];
  const int z = blockIdx.z;
  const float* s = src + (size_t)z * 4096 * 256;
  bf16* d = dst + (size_t)z * 256 * 4096;
  const int n0 = blockIdx.x * 64, d0 = blockIdx.y * 64;
  const int tx = threadIdx.x & 31, ty = threadIdx.x >> 5;
#pragma unroll
  for (int i = 0; i < 8; ++i) {
    const int r = ty + i * 8;
    const float2 v = *(const float2*)(s + (size_t)(n0 + r) * 256 + d0 + tx * 2);
    tile[r][tx * 2] = v.x;
    tile[r][tx * 2 + 1] = v.y;
  }
  __syncthreads();
#pragma unroll
  for (int i = 0; i < 8; ++i) {
    const int c = ty + i * 8;
    __hip_bfloat162 p;
    p.x = __float2bfloat16(tile[tx * 2][c]);
    p.y = __float2bfloat16(tile[tx * 2 + 1][c]);
    *(__hip_bfloat162*)(d + (size_t)(d0 + c) * 4096 + n0 + tx * 2) = p;
  }
}

// WbigT bf16 [128][1280]
__global__ void wbig(const float* __restrict__ Wk, const float* __restrict__ Wl,
                     bf16* __restrict__ WbT) {
  int idx = blockIdx.x * 256 + threadIdx.x;
  if (idx >= 128 * 1280) return;
  int j = idx / 1280, k = idx % 1280;
  int o = j & 63;
  float v = 0.f;
  if (k < 256)
    v = Wk[k * 64 + o] + Wl[k * 128 + j];
  else if (k < 512)
    v = (j < 64) ? Wk[16384 + (k - 256) * 64 + o] : 0.f;
  else if (k < 768)
    v = (j < 64) ? Wk[32768 + (k - 512) * 64 + o] : 0.f;
  else if (k < 1024)
    v = (j >= 64) ? Wk[16384 + (k - 768) * 64 + o] : 0.f;
  else
    v = (j >= 64) ? Wk[32768 + (k - 1024) * 64 + o] : 0.f;
  WbT[idx] = __float2bfloat16(v);
}

// S = x x^T tile + adjacency/spline epilogue -> bk, wk bf16 [4096][4096].
// Spline pair via 2048-entry LDS LUT over t=exp(-d2/512); paired-column
// dword stores via shfl_xor(1). LDS = 40K.
// bounds(256,2): R5-proven regalloc (VGPR 92, zero spill). bounds=3/4 make
// the compiler target the 128-reg config and spill (+16MB WRITE, R6/R7).
// Kernel is write-drain-bound ~2.8 TB/s; floor ~48us for 134MB.
__global__ __launch_bounds__(256, 2) void gemm_s(const bf16* __restrict__ U,
                                                 const float* __restrict__ sq,
                                                 bf16* __restrict__ kmat) {
  __shared__ __align__(16) bf16 As[128 * 64];
  __shared__ __align__(16) bf16 Bs[128 * 64];
  __shared__ unsigned lut[2048];
  const int tid = threadIdx.x;
  for (int i = tid; i < 2048; i += 256) {
    float t = (i + 0.5f) * (1.f / 2048.f);
    float bv = b3(4.f * t);
    float wv = b3(8.f * t) - b3(8.f * t - 4.f);
    lut[i] = (unsigned)f2bf(bv) | ((unsigned)f2bf(wv) << 16);
  }
  const int z = blockIdx.z;
  const bf16* A = U + (size_t)z * 4096 * 1280 + (size_t)blockIdx.x * 128 * 1280;
  const bf16* B = U + (size_t)z * 4096 * 1280 + (size_t)blockIdx.y * 128 * 1280;
  v4f acc[4][4];
#pragma unroll
  for (int a = 0; a < 4; ++a)
#pragma unroll
    for (int b2 = 0; b2 < 4; ++b2) acc[a][b2] = (v4f){0.f, 0.f, 0.f, 0.f};
  mfma_loop<4, 64>(A, B, 1280, 1280, 256, As, Bs, acc);
  const int wave = tid >> 6, lane = tid & 63;
  const int quad = lane >> 4, r16 = lane & 15;
  const int wm = (wave >> 1) * 64, wn = (wave & 1) * 64;
  const float* sqr = sq + (size_t)z * 4096;
  unsigned short* bk = (unsigned short*)(kmat + (size_t)(z * 2) * 4096 * 4096);
  unsigned short* wk = bk + (size_t)4096 * 4096;
  const int i0 = blockIdx.x * 128 + wm + quad * 4;
  const int j0 = blockIdx.y * 128 + wn + r16;
  const int par = lane & 1;  // 0: stores rows r=0,1 ; 1: rows r=2,3
  const int jc = j0 - par;   // even column of this lane's pair
  float sqj[4];
#pragma unroll
  for (int ni = 0; ni < 4; ++ni) sqj[ni] = sqr[j0 + ni * 16];
  const float c = -1.4426950408889634f / 512.f;  // -log2(e)/512
#pragma unroll
  for (int mi = 0; mi < 4; ++mi) {
#pragma unroll
    for (int ni = 0; ni < 4; ++ni) {
      unsigned pv[4];
#pragma unroll
      for (int r = 0; r < 4; ++r) {
        float s = acc[mi][ni][r];
        float d2 = fmaxf(sqr[i0 + mi * 16 + r] + sqj[ni] - 2.f * s, 0.f);
        float t = __builtin_amdgcn_exp2f(d2 * c);
        int idx = (int)fminf(t * 2048.f, 2047.f);
        pv[r] = lut[idx];
      }
      unsigned ov[4];
#pragma unroll
      for (int r = 0; r < 4; ++r) ov[r] = __shfl_xor((int)pv[r], 1, 64);
#pragma unroll
      for (int rr = 0; rr < 2; ++rr) {
        const int r = par * 2 + rr;
        const unsigned a = pv[r], b2 = ov[r];
        const unsigned lo = par ? b2 : a;  // left (even) column
        const unsigned hi = par ? a : b2;  // right (odd) column
        const unsigned bkd = (lo & 0xffffu) | (hi << 16);
        const unsigned wkd = (lo >> 16) | (hi & 0xffff0000u);
        const int i = i0 + mi * 16 + r;
        const size_t off = (size_t)i * 4096 + jc + ni * 16;
        *(unsigned*)(bk + off) = bkd;
        *(unsigned*)(wk + off) = wkd;
      }
    }
  }
}

// h-partial = K[:, split] @ H[split, :] : split-K x4, BK=64, 128x128 tile.
// A = kernel matrix [4096][4096] bf16, Bt = H^T bf16 [256][4096].
// writes bf16 partials (packed pairs, dword stores) to
// hpart[split][z][4096][256]. bf16 partials cost ~0.2% rel — within budget.
__global__ __launch_bounds__(256, 4) void gemm_h(const bf16* __restrict__ kmat,
                                                 const bf16* __restrict__ BtBase,
                                                 bf16* __restrict__ hpart,
                                                 int btShift) {
  __shared__ __align__(16) bf16 As[128 * 64];
  __shared__ __align__(16) bf16 Bs[128 * 64];
  const int bz = blockIdx.z;
  const int z = bz >> 2, split = bz & 3;
  const int kk0 = split * 1024;
  const bf16* A =
      kmat + (size_t)z * 4096 * 4096 + (size_t)blockIdx.x * 128 * 4096 + kk0;
  const bf16* B = BtBase + (size_t)(z >> btShift) * 256 * 4096 +
                  (size_t)blockIdx.y * 128 * 4096 + kk0;
  v4f acc[4][4];
#pragma unroll
  for (int a = 0; a < 4; ++a)
#pragma unroll
    for (int b2 = 0; b2 < 4; ++b2) acc[a][b2] = (v4f){0.f, 0.f, 0.f, 0.f};
  mfma_loop<4, 64>(A, B, 4096, 4096, 1024, As, Bs, acc);
  const int tid = threadIdx.x, wave = tid >> 6, lane = tid & 63;
  const int quad = lane >> 4, r16 = lane & 15;
  const int wm = (wave >> 1) * 64, wn = (wave & 1) * 64;
  bf16* H = hpart + ((size_t)split * 4 + z) * 4096 * 256;
  const int i0 = blockIdx.x * 128 + wm + quad * 4;
  const int j0 = blockIdx.y * 128 + wn + r16;
  const int par = lane & 1;
  const int jc = j0 - par;
#pragma unroll
  for (int mi = 0; mi < 4; ++mi) {
#pragma unroll
    for (int ni = 0; ni < 4; ++ni) {
      unsigned pv[4];
#pragma unroll
      for (int r = 0; r < 4; ++r) pv[r] = (unsigned)f2bf(acc[mi][ni][r]);
      unsigned ov[4];
#pragma unroll
      for (int r = 0; r < 4; ++r) ov[r] = __shfl_xor((int)pv[r], 1, 64);
#pragma unroll
      for (int rr = 0; rr < 2; ++rr) {
        const int r = par * 2 + rr;
        const unsigned a = pv[r], b2 = ov[r];
        const unsigned lo = par ? b2 : a;
        const unsigned hi = par ? a : b2;
        const int i = i0 + mi * 16 + r;
        *(unsigned*)(H + (size_t)i * 256 + jc + ni * 16) = lo | (hi << 16);
      }
    }
  }
}

// sum the four bf16 split-K partials; write bf16 slice into U[:, uoff..] and
// (pass 1 only) transposed bf16 into hT [z][256][4096].
__global__ void reduceT(const bf16* __restrict__ hpart, bf16* __restrict__ U,
                        bf16* __restrict__ hT, int uoffBase) {
  __shared__ float tile[64][65];
  const int z = blockIdx.z;
  const int b = z >> 1, kern = z & 1;
  const int uoff = uoffBase + kern * 512;
  const int n0 = blockIdx.x * 64, d0 = blockIdx.y * 64;
  const int tx = threadIdx.x & 31, ty = threadIdx.x >> 5;
  const size_t sstride = (size_t)4 * 4096 * 256;
  const bf16* s0 = hpart + (size_t)z * 4096 * 256;
#pragma unroll
  for (int i = 0; i < 8; ++i) {
    const int r = ty + i * 8;
    const size_t off = (size_t)(n0 + r) * 256 + d0 + tx * 2;
    float vx = 0.f, vy = 0.f;
#pragma unroll
    for (int k = 0; k < 4; ++k) {
      const unsigned dw = *(const unsigned*)(s0 + k * sstride + off);
      vx += bflo(dw);
      vy += bfhi(dw);
    }
    tile[r][tx * 2] = vx;
    tile[r][tx * 2 + 1] = vy;
    __hip_bfloat162 p;
    p.x = __float2bfloat16(vx);
    p.y = __float2bfloat16(vy);
    *(__hip_bfloat162*)(U + (size_t)(b * 4096 + n0 + r) * 1280 + uoff + d0 +
                        tx * 2) = p;
  }
  if (hT) {
    __syncthreads();
#pragma unroll
    for (int i = 0; i < 8; ++i) {
      const int c = ty + i * 8;
      __hip_bfloat162 p;
      p.x = __float2bfloat16(tile[tx * 2][c]);
      p.y = __float2bfloat16(tile[tx * 2 + 1][c]);
      *(__hip_bfloat162*)(hT + (size_t)z * 256 * 4096 + (size_t)(d0 + c) * 4096 +
                          n0 + tx * 2) = p;
    }
  }
}

// out = relu(U @ Wbig + b_lin), M=8192, K=1280, N=128
__global__ __launch_bounds__(256, 4) void gemm_proj(
    const bf16* __restrict__ U, const bf16* __restrict__ WbT,
    const float* __restrict__ blin, float* __restrict__ out) {
  __shared__ __align__(16) bf16 As[128 * 64];
  __shared__ __align__(16) bf16 Bs[64 * 64];
  const bf16* A = U + (size_t)blockIdx.x * 128 * 1280;
  const bf16* B = WbT + (size_t)blockIdx.y * 64 * 1280;
  v4f acc[4][2];
#pragma unroll
  for (int a = 0; a < 4; ++a)
#pragma unroll
    for (int b2 = 0; b2 < 2; ++b2) acc[a][b2] = (v4f){0.f, 0.f, 0.f, 0.f};
  mfma_loop<2, 64>(A, B, 1280, 1280, 1280, As, Bs, acc);
  const int tid = threadIdx.x, wave = tid >> 6, lane = tid & 63;
  const int quad = lane >> 4, r16 = lane & 15;
  const int wm = (wave >> 1) * 64, wn = (wave & 1) * 32;
  const int i0 = blockIdx.x * 128 + wm + quad * 4;
  const int j0 = blockIdx.y * 64 + wn + r16;
#pragma unroll
  for (int mi = 0; mi < 4; ++mi)
#pragma unroll
    for (int r = 0; r < 4; ++r) {
      const int i = i0 + mi * 16 + r;
#pragma unroll
      for (int ni = 0; ni < 2; ++ni) {
        const int j = j0 + ni * 16;
        out[(size_t)i * 128 + j] = fmaxf(acc[mi][ni][r] + blin[j], 0.f);
      }
    }
}

extern "C" void kernel_launch(void* const* d_in, const int* in_sizes, int n_in,
                              void* d_out, int out_size, void* d_ws,
                              size_t ws_size, hipStream_t stream) {
  const float* x = (const float*)d_in[0];
  const float* Wk = (const float*)d_in[1];
  const float* Wlin = (const float*)d_in[2];
  const float* blin = (const float*)d_in[3];
  float* out = (float*)d_out;
  char* w = (char*)d_ws;
  // workspace layout (bytes):
  bf16* kmat = (bf16*)(w);                // 4 * 4096*4096 * 2  = 134217728
  bf16* hpart = (bf16*)(w + 134217728);   // 4 * 4*4096*256*2   = 33554432
  bf16* h1T = (bf16*)(w + 201326592);     // 4 * 256*4096 * 2   = 8388608
  bf16* xhT = (bf16*)(w + 209715200);     // 2 * 256*4096 * 2   = 4194304
  bf16* U = (bf16*)(w + 213909504);       // 8192*1280 * 2      = 20971520
  bf16* WbT = (bf16*)(w + 234881024);     // 128*1280 * 2       = 327680
  float* sqv = (float*)(w + 235208704);   // 8192 * 4           = 32768
  // total ~235.2 MB

  prep<<<dim3(4096, 2), 256, 0, stream>>>(x, U, sqv);
  transk<<<dim3(64, 4, 2), 256, 0, stream>>>(x, xhT);
  wbig<<<dim3(640), 256, 0, stream>>>(Wk, Wlin, WbT);
  gemm_s<<<dim3(32, 32, 2), 256, 0, stream>>>(U, sqv, kmat);
  // pass 1: h1 = K @ x
  gemm_h<<<dim3(32, 2, 16), 256, 0, stream>>>(kmat, xhT, hpart, 1);
  reduceT<<<dim3(64, 4, 4), 256, 0, stream>>>(hpart, U, h1T, 256);
  // pass 2: h2 = K @ h1
  gemm_h<<<dim3(32, 2, 16), 256, 0, stream>>>(kmat, h1T, hpart, 0);
  reduceT<<<dim3(64, 4, 4), 256, 0, stream>>>(hpart, U, nullptr, 512);
  gemm_proj<<<dim3(64, 2), 256, 0, stream>>>(U, WbT, blin, out);
}